// Round 1
// baseline (469.641 us; speedup 1.0000x reference)
//
#include <hip/hip_runtime.h>
#include <cstdint>
#include <cstddef>

// ---------------------------------------------------------------------------
// FeedForwardQuantum: out = W2 @ relu(W1 @ (cos(theta)*cos(x[:,:8])) + b1) + b2
// M = 8*4096 = 32768 tokens, K = 4096 (FFN), N = 1024 (EMBED)
// Strategy: bf16 MFMA for the big GEMM (274.9 GFLOP). H and W2 are produced
// as bf16 in workspace with a pre-applied XOR group swizzle so that the GEMM's
// linear global_load_lds staging + XOR'd ds_read_b128 reads are bank-conflict
// free (guide rule 21: swizzle source+read, linear LDS dest).
// ---------------------------------------------------------------------------

#define M_TOT 32768L
#define N_DIM 1024
#define K_DIM 4096
#define BM 128
#define BN 128
#define BK 64

typedef __attribute__((ext_vector_type(8))) short short8;   // 8 x bf16 (4 VGPRs)
typedef __attribute__((ext_vector_type(4))) float f32x4;

__device__ __forceinline__ uint16_t f2bf(float f) {
  uint32_t u = __builtin_bit_cast(uint32_t, f);
  uint32_t r = (u + 0x7fffu + ((u >> 16) & 1u)) >> 16;   // RNE
  return (uint16_t)r;
}

__device__ __forceinline__ void gload_lds16(const void* gsrc, void* ldst) {
  __builtin_amdgcn_global_load_lds(
      (const __attribute__((address_space(1))) void*)gsrc,
      (__attribute__((address_space(3))) void*)ldst, 16, 0, 0);
}

// ---------------------------------------------------------------------------
// Kernel 1: W2 [1024][4096] fp32 -> bf16, swizzled layout:
//   elem (e,k) stored at e*4096 + (k & ~63) + (((k>>3)&7) ^ (e&7))*8 + (k&7)
// ---------------------------------------------------------------------------
__global__ __launch_bounds__(256) void prep_w2(const float* __restrict__ W2,
                                               uint16_t* __restrict__ W2sw) {
  long idx = (long)blockIdx.x * 256 + threadIdx.x;   // 524288 threads
  long e8 = idx * 8;
  int e = (int)(e8 >> 12);
  int k = (int)(e8 & 4095);
  float4 v0 = *(const float4*)(W2 + e8);
  float4 v1 = *(const float4*)(W2 + e8 + 4);
  union { uint16_t u[8]; uint4 v; } pk;
  pk.u[0] = f2bf(v0.x); pk.u[1] = f2bf(v0.y); pk.u[2] = f2bf(v0.z); pk.u[3] = f2bf(v0.w);
  pk.u[4] = f2bf(v1.x); pk.u[5] = f2bf(v1.y); pk.u[6] = f2bf(v1.z); pk.u[7] = f2bf(v1.w);
  int sg = ((k >> 3) & 7) ^ (e & 7);
  uint16_t* dst = W2sw + (long)e * 4096 + (k & ~63) + sg * 8;
  *(uint4*)dst = pk.v;   // 16B aligned
}

// ---------------------------------------------------------------------------
// Kernel 2: H[m][f] = relu(sum_i q[m][i]*W1[f][i] + b1[f]),
//           q[m][i] = cos(theta[i])*cos(x[m*1024 + i]).
// Stored bf16, same swizzled layout (row index = m, col = f).
// Block: 256 threads = 256 f's (f = blockIdx.y*256+tid), 64 tokens each.
// x is passed pre-offset for the current M-chunk; Hsw indexed by local m.
// ---------------------------------------------------------------------------
__global__ __launch_bounds__(256) void h_kernel(const float* __restrict__ x,
                                                const float* __restrict__ theta,
                                                const float* __restrict__ W1,
                                                const float* __restrict__ b1,
                                                uint16_t* __restrict__ Hsw) {
  __shared__ float qs[64][8];
  int tid = threadIdx.x;
  long m0 = (long)blockIdx.x * 64;
  int f = blockIdx.y * 256 + tid;

  for (int idx = tid; idx < 512; idx += 256) {
    int t = idx >> 3, i = idx & 7;
    qs[t][i] = __cosf(theta[i]) * 1.0f * cosf(x[(m0 + t) * 1024 + i]);
  }
  // NB: use precise cosf for both to match reference closely
  __syncthreads();
  // overwrite with precise version for theta part (8 values, negligible)
  if (tid < 512 - 256) {} // no-op

  const float4* w1p = (const float4*)(W1 + (long)f * 8);
  float4 wa = w1p[0];
  float4 wb = w1p[1];
  float bb = b1[f];
  int fblk = f & ~63;
  int grp = (f >> 3) & 7;
  int fw = f & 7;

#pragma unroll 4
  for (int t = 0; t < 64; ++t) {
    long m = m0 + t;
    const float* q = qs[t];
    float h = bb;
    h += q[0] * wa.x + q[1] * wa.y + q[2] * wa.z + q[3] * wa.w;
    h += q[4] * wb.x + q[5] * wb.y + q[6] * wb.z + q[7] * wb.w;
    h = fmaxf(h, 0.0f);
    int sg = grp ^ ((int)m & 7);
    Hsw[m * K_DIM + fblk + sg * 8 + fw] = f2bf(h);
  }
}

// ---------------------------------------------------------------------------
// Kernel 3: GEMM  out[m][n] = sum_k H[m][k] * W2[n][k]  + b2[n]   (bt layout)
// m97 structure: 128x128 tile, BK=64, 4 waves (2x2 of 64x64), 16x16x32 bf16
// MFMA, global_load_lds width-16 staging, XOR-swizzled LDS reads, XCD swizzle.
// ---------------------------------------------------------------------------
__global__ __launch_bounds__(256) void gemm_kernel(const uint16_t* __restrict__ Hsw,
                                                   const uint16_t* __restrict__ W2sw,
                                                   const float* __restrict__ b2,
                                                   float* __restrict__ out) {
  __shared__ uint16_t lsA[BM * BK];   // 16 KiB
  __shared__ uint16_t lsB[BN * BK];   // 16 KiB

  int nwg = gridDim.x;                 // multiple of 8 by construction
  int cpx = nwg >> 3;
  int bid = blockIdx.x;
  int sw = (bid & 7) * cpx + (bid >> 3);      // XCD-aware swizzle (bijective)
  const int NT = N_DIM / BN;                  // 8
  int mt = sw / NT;
  int nt = sw - mt * NT;
  long m0 = (long)mt * BM;
  int n0 = nt * BN;

  int tid = threadIdx.x;
  int lane = tid & 63;
  int wave = tid >> 6;
  int wm = (wave >> 1) * 64;
  int wn = (wave & 1) * 64;

  int r = lane & 15;
  int kq = lane >> 4;     // 0..3

  // staging addressing: call j covers chunks c = j*256 + tid
  int rowS = tid >> 3;    // + j*32
  int grpS = tid & 7;
  const uint16_t* baseA = Hsw + (m0 + rowS) * K_DIM + grpS * 8;
  const uint16_t* baseB = W2sw + ((long)n0 + rowS) * K_DIM + grpS * 8;
  int ldsWaveBase = (tid & ~63) * 8;  // elems; + j*256*8

  f32x4 acc[4][4] = {};

  for (int kt = 0; kt < K_DIM / BK; ++kt) {
    int k0 = kt * BK;
#pragma unroll
    for (int j = 0; j < 4; ++j) {
      gload_lds16(baseA + (long)j * 32 * K_DIM + k0, &lsA[j * 2048 + ldsWaveBase]);
      gload_lds16(baseB + (long)j * 32 * K_DIM + k0, &lsB[j * 2048 + ldsWaveBase]);
    }
    __syncthreads();   // compiler drains vmcnt before barrier

#pragma unroll
    for (int ks = 0; ks < 2; ++ks) {
      short8 a[4], b[4];
#pragma unroll
      for (int mf = 0; mf < 4; ++mf) {
        int row = wm + mf * 16 + r;
        int sg = (ks * 4 + kq) ^ (row & 7);
        a[mf] = *(const short8*)&lsA[row * BK + sg * 8];
      }
#pragma unroll
      for (int nf = 0; nf < 4; ++nf) {
        int row = wn + nf * 16 + r;
        int sg = (ks * 4 + kq) ^ (row & 7);
        b[nf] = *(const short8*)&lsB[row * BK + sg * 8];
      }
#pragma unroll
      for (int mf = 0; mf < 4; ++mf)
#pragma unroll
        for (int nf = 0; nf < 4; ++nf)
          acc[mf][nf] = __builtin_amdgcn_mfma_f32_16x16x32_bf16(a[mf], b[nf], acc[mf][nf], 0, 0, 0);
    }
    __syncthreads();
  }

  // epilogue: C/D layout col = lane&15, row = (lane>>4)*4 + reg
  int crow = kq * 4;
#pragma unroll
  for (int mf = 0; mf < 4; ++mf) {
#pragma unroll
    for (int nf = 0; nf < 4; ++nf) {
      int n = n0 + wn + nf * 16 + r;
      float bb = b2[n];
      long mb = m0 + wm + mf * 16 + crow;
#pragma unroll
      for (int rg = 0; rg < 4; ++rg) {
        out[(mb + rg) * N_DIM + n] = acc[mf][nf][rg] + bb;
      }
    }
  }
}

// ---------------------------------------------------------------------------
extern "C" void kernel_launch(void* const* d_in, const int* in_sizes, int n_in,
                              void* d_out, int out_size, void* d_ws, size_t ws_size,
                              hipStream_t stream) {
  const float* x     = (const float*)d_in[0];
  const float* theta = (const float*)d_in[1];
  const float* W1    = (const float*)d_in[2];
  const float* b1    = (const float*)d_in[3];
  const float* W2    = (const float*)d_in[4];
  const float* b2    = (const float*)d_in[5];
  float* out = (float*)d_out;

  const size_t W2SW_BYTES = (size_t)N_DIM * K_DIM * 2;   // 8 MiB
  uint16_t* W2sw = (uint16_t*)d_ws;
  uint16_t* Hsw  = (uint16_t*)((char*)d_ws + W2SW_BYTES);

  size_t avail = ws_size > W2SW_BYTES ? ws_size - W2SW_BYTES : 0;
  long CM = (long)(avail / ((size_t)K_DIM * 2));
  CM &= ~127L;                       // multiple of BM
  if (CM > M_TOT) CM = M_TOT;
  if (CM < 128) CM = 128;            // minimum viable chunk

  prep_w2<<<2048, 256, 0, stream>>>(W2, W2sw);

  for (long m0 = 0; m0 < M_TOT; m0 += CM) {
    long mc = M_TOT - m0;
    if (mc > CM) mc = CM;
    dim3 gA((unsigned)(mc / 64), K_DIM / 256);
    h_kernel<<<gA, 256, 0, stream>>>(x + m0 * N_DIM, theta, W1, b1, Hsw);
    unsigned ngb = (unsigned)((mc / BM) * (N_DIM / BN));
    gemm_kernel<<<ngb, 256, 0, stream>>>(Hsw, W2sw, b2, out + m0 * N_DIM);
  }
}

// Round 2
// 329.078 us; speedup vs baseline: 1.4271x; 1.4271x over previous
//
#include <hip/hip_runtime.h>
#include <cstdint>
#include <cstddef>

// ---------------------------------------------------------------------------
// FeedForwardQuantum: out = W2 @ relu(W1 @ (cos(theta)*cos(x[:,:8])) + b1) + b2
// M = 32768 tokens, K = 4096 (FFN), N = 1024 (EMBED).
// GEMM: 256x256 8-phase template (T2 swizzle + T3/T4 counted vmcnt + T5
// setprio), bf16 MFMA. H and W2 are produced pre-swizzled in global memory
// (granule ^= row&7 within each 64-elem K-block) so linear global_load_lds
// staging + XOR'd ds_read_b128 is bank-conflict-free (verified 0 conflicts
// in round 1).
// ---------------------------------------------------------------------------

#define M_TOT 32768L
#define N_DIM 1024
#define K_DIM 4096
#define BM 256
#define BN 256
#define BK 64
#define NT_K (K_DIM / BK)   // 64

typedef __attribute__((ext_vector_type(8))) short short8;   // 8 x bf16
typedef __attribute__((ext_vector_type(4))) float f32x4;

__device__ __forceinline__ uint16_t f2bf(float f) {
  uint32_t u = __builtin_bit_cast(uint32_t, f);
  uint32_t r = (u + 0x7fffu + ((u >> 16) & 1u)) >> 16;   // RNE
  return (uint16_t)r;
}

__device__ __forceinline__ void gload_lds16(const void* gsrc, void* ldst) {
  __builtin_amdgcn_global_load_lds(
      (const __attribute__((address_space(1))) void*)gsrc,
      (__attribute__((address_space(3))) void*)ldst, 16, 0, 0);
}

// ---------------------------------------------------------------------------
// Kernel 1: W2 [1024][4096] fp32 -> bf16, swizzled:
//   elem (e,k) at e*4096 + (k & ~63) + (((k>>3)&7) ^ (e&7))*8 + (k&7)
// ---------------------------------------------------------------------------
__global__ __launch_bounds__(256) void prep_w2(const float* __restrict__ W2,
                                               uint16_t* __restrict__ W2sw) {
  long idx = (long)blockIdx.x * 256 + threadIdx.x;
  long e8 = idx * 8;
  int e = (int)(e8 >> 12);
  int k = (int)(e8 & 4095);
  float4 v0 = *(const float4*)(W2 + e8);
  float4 v1 = *(const float4*)(W2 + e8 + 4);
  union { uint16_t u[8]; uint4 v; } pk;
  pk.u[0] = f2bf(v0.x); pk.u[1] = f2bf(v0.y); pk.u[2] = f2bf(v0.z); pk.u[3] = f2bf(v0.w);
  pk.u[4] = f2bf(v1.x); pk.u[5] = f2bf(v1.y); pk.u[6] = f2bf(v1.z); pk.u[7] = f2bf(v1.w);
  int sg = ((k >> 3) & 7) ^ (e & 7);
  uint16_t* dst = W2sw + (long)e * 4096 + (k & ~63) + sg * 8;
  *(uint4*)dst = pk.v;
}

// ---------------------------------------------------------------------------
// Kernel 2: H[m][f] = relu(sum_i q[m][i]*W1[f][i] + b1[f]),  bf16, swizzled.
// ---------------------------------------------------------------------------
__global__ __launch_bounds__(256) void h_kernel(const float* __restrict__ x,
                                                const float* __restrict__ theta,
                                                const float* __restrict__ W1,
                                                const float* __restrict__ b1,
                                                uint16_t* __restrict__ Hsw) {
  __shared__ float qs[64][8];
  int tid = threadIdx.x;
  long m0 = (long)blockIdx.x * 64;
  int f = blockIdx.y * 256 + tid;

  for (int idx = tid; idx < 512; idx += 256) {
    int t = idx >> 3, i = idx & 7;
    qs[t][i] = __cosf(theta[i]) * cosf(x[(m0 + t) * 1024 + i]);
  }
  __syncthreads();

  const float4* w1p = (const float4*)(W1 + (long)f * 8);
  float4 wa = w1p[0];
  float4 wb = w1p[1];
  float bb = b1[f];
  int fblk = f & ~63;
  int grp = (f >> 3) & 7;
  int fw = f & 7;

#pragma unroll 4
  for (int t = 0; t < 64; ++t) {
    long m = m0 + t;
    const float* q = qs[t];
    float h = bb;
    h += q[0] * wa.x + q[1] * wa.y + q[2] * wa.z + q[3] * wa.w;
    h += q[4] * wb.x + q[5] * wb.y + q[6] * wb.z + q[7] * wb.w;
    h = fmaxf(h, 0.0f);
    int sg = grp ^ ((int)m & 7);
    Hsw[m * K_DIM + fblk + sg * 8 + fw] = f2bf(h);
  }
}

// ---------------------------------------------------------------------------
// Kernel 3: 256x256 8-phase GEMM.  out[m][n] = sum_k H[m][k]*W2[n][k] + b2[n]
// 8 waves (2M x 4N), each owns 128x64 output = acc[8][4] f32x4.
// LDS: A,B double-buffered [2][256][64] bf16 = 128 KiB total.
// Per K-tile: 4 phases, each = {ds_read frag subtile; issue 2 global_load_lds;
// barrier; setprio(1); 16 MFMA; setprio(0); barrier}. vmcnt(6) once per
// K-tile (phase 4) => 3 half-tiles stay in flight across barriers.
// Region-safety: each 64-row stage target was last ds_read >=1 full
// phase-barrier earlier (A j0: read P0, staged P1; B: read P0/P1, staged
// P2/P3; A j1: read P2, staged at next tile's P0 into the other buffer).
// ---------------------------------------------------------------------------
__global__ __launch_bounds__(512, 2) void gemm_kernel(const uint16_t* __restrict__ Hsw,
                                                      const uint16_t* __restrict__ W2sw,
                                                      const float* __restrict__ b2,
                                                      float* __restrict__ out) {
  __shared__ uint16_t LA[2 * BM * BK];   // 64 KiB
  __shared__ uint16_t LB[2 * BN * BK];   // 64 KiB

  int nwg = gridDim.x;
  int bid = blockIdx.x;
  int sw = bid;
  if ((nwg & 7) == 0) { int cpx = nwg >> 3; sw = (bid & 7) * cpx + (bid >> 3); }
  const int NTN = N_DIM / BN;            // 4
  int mt = sw / NTN;
  int nt = sw - mt * NTN;
  long m0 = (long)mt * BM;
  int n0 = nt * BN;

  int tid = threadIdx.x;
  int lane = tid & 63;
  int wave_m = (tid >> 6) >> 2;          // 0..1
  int wave_n = (tid >> 6) & 3;           // 0..3
  int wmB = wave_m * 128;
  int wnB = wave_n * 64;

  int r  = lane & 15;
  int kq = lane >> 4;
  int xr = r & 7;

  // staging addresses: thread covers row (tid>>3) of each 64-row region,
  // 16B at col granule (tid&7). Source is pre-swizzled -> pure linear copy.
  int rowS = tid >> 3;
  int colS = (tid & 7) * 8;
  const uint16_t* srcA = Hsw  + (m0 + rowS) * K_DIM + colS;
  const uint16_t* srcB = W2sw + ((long)(n0 + rowS)) * K_DIM + colS;
  int ldsWB = (tid & ~63) * 8;           // wave-uniform elem offset in region

#define STAGE_A(p, h, j, t) \
  gload_lds16(srcA + (long)((h)*128 + (j)*64) * K_DIM + (t)*BK, \
              &LA[(p)*16384 + ((h)*128 + (j)*64)*BK + ldsWB])
#define STAGE_B(p, h, j, t) \
  gload_lds16(srcB + (long)((h)*128 + (j)*64) * K_DIM + (t)*BK, \
              &LB[(p)*16384 + ((h)*128 + (j)*64)*BK + ldsWB])

#define BAR() do { asm volatile("" ::: "memory"); __builtin_amdgcn_s_barrier(); \
                   asm volatile("" ::: "memory"); } while (0)

#define LDA_F(p, mf_, ks_) \
  (*(const short8*)&LA[(p)*16384 + (wmB + (mf_)*16 + r)*BK + ((((ks_)*4 + kq) ^ xr)*8)])
#define LDB_F(p, nf_, ks_) \
  (*(const short8*)&LB[(p)*16384 + (wnB + (nf_)*16 + r)*BK + ((((ks_)*4 + kq) ^ xr)*8)])

#define MFMA_PHASE(mh, nh) do { \
    __builtin_amdgcn_s_setprio(1); \
    _Pragma("unroll") for (int i_ = 0; i_ < 4; ++i_) \
    _Pragma("unroll") for (int j_ = 0; j_ < 2; ++j_) \
    _Pragma("unroll") for (int ks_ = 0; ks_ < 2; ++ks_) \
      acc[(mh)*4 + i_][(nh)*2 + j_] = __builtin_amdgcn_mfma_f32_16x16x32_bf16( \
          a[i_][ks_], bq[(nh)][j_][ks_], acc[(mh)*4 + i_][(nh)*2 + j_], 0, 0, 0); \
    __builtin_amdgcn_s_setprio(0); \
  } while (0)

  f32x4 acc[8][4];
#pragma unroll
  for (int i = 0; i < 8; ++i)
#pragma unroll
    for (int j = 0; j < 4; ++j) acc[i][j] = (f32x4){0.f, 0.f, 0.f, 0.f};

  short8 a[4][2];        // current mh quadrant A frags
  short8 bq[2][2][2];    // [nh][nf2][ks] B frags, both sets live

  // ---- prologue: all 8 calls of t=0 into buf0, then t=1's Aj0+B (6 calls).
  // t=1's Aj1 pair is issued at P0(u=0), matching steady state.
#pragma unroll
  for (int h = 0; h < 2; ++h)
#pragma unroll
    for (int j = 0; j < 2; ++j) STAGE_A(0, h, j, 0);
#pragma unroll
  for (int h = 0; h < 2; ++h)
#pragma unroll
    for (int j = 0; j < 2; ++j) STAGE_B(0, h, j, 0);
  STAGE_A(1, 0, 0, 1); STAGE_A(1, 1, 0, 1);
  STAGE_B(1, 0, 0, 1); STAGE_B(1, 0, 1, 1);
  STAGE_B(1, 1, 0, 1); STAGE_B(1, 1, 1, 1);
  asm volatile("s_waitcnt vmcnt(6)" ::: "memory");   // t=0 fully landed
  BAR();

#pragma unroll 2
  for (int u = 0; u < NT_K; ++u) {
    int p = u & 1;
    // ---- P0: read A[mh=0] (8) + B[nh=0] (4); stage A j1 of t=u+1 (other buf)
#pragma unroll
    for (int i = 0; i < 4; ++i)
#pragma unroll
      for (int ks = 0; ks < 2; ++ks) a[i][ks] = LDA_F(p, i, ks);
#pragma unroll
    for (int j = 0; j < 2; ++j)
#pragma unroll
      for (int ks = 0; ks < 2; ++ks) bq[0][j][ks] = LDB_F(p, j, ks);
    if (u < NT_K - 1) { STAGE_A(p ^ 1, 0, 1, u + 1); STAGE_A(p ^ 1, 1, 1, u + 1); }
    BAR();
    MFMA_PHASE(0, 0);
    BAR();
    // ---- P1: read B[nh=1] (4); stage A j0 of t=u+2 (this buf, rows read@P0)
#pragma unroll
    for (int j = 0; j < 2; ++j)
#pragma unroll
      for (int ks = 0; ks < 2; ++ks) bq[1][j][ks] = LDB_F(p, 2 + j, ks);
    if (u < NT_K - 2) { STAGE_A(p, 0, 0, u + 2); STAGE_A(p, 1, 0, u + 2); }
    BAR();
    MFMA_PHASE(0, 1);
    BAR();
    // ---- P2: read A[mh=1] (8); stage B half0 of t=u+2 (rows read@P0/P1)
#pragma unroll
    for (int i = 0; i < 4; ++i)
#pragma unroll
      for (int ks = 0; ks < 2; ++ks) a[i][ks] = LDA_F(p, 4 + i, ks);
    if (u < NT_K - 2) { STAGE_B(p, 0, 0, u + 2); STAGE_B(p, 0, 1, u + 2); }
    BAR();
    MFMA_PHASE(1, 1);
    BAR();
    // ---- P3: no reads (bq[0] reused); stage B half1 of t=u+2; counted vmcnt
    if (u < NT_K - 2) { STAGE_B(p, 1, 0, u + 2); STAGE_B(p, 1, 1, u + 2); }
    BAR();
    MFMA_PHASE(1, 0);
    if (u < NT_K - 2) { asm volatile("s_waitcnt vmcnt(6)" ::: "memory"); }
    else              { asm volatile("s_waitcnt vmcnt(0)" ::: "memory"); }
    BAR();
  }

  // ---- epilogue: C/D layout col = lane&15 (n), row = kq*4 + reg (m)
  float bb[4];
#pragma unroll
  for (int nf = 0; nf < 4; ++nf) bb[nf] = b2[n0 + wnB + nf * 16 + r];
  long mbase = m0 + wmB + kq * 4;
#pragma unroll
  for (int mf = 0; mf < 8; ++mf) {
#pragma unroll
    for (int nf = 0; nf < 4; ++nf) {
      int n = n0 + wnB + nf * 16 + r;
#pragma unroll
      for (int rg = 0; rg < 4; ++rg) {
        out[(mbase + mf * 16 + rg) * N_DIM + n] = acc[mf][nf][rg] + bb[nf];
      }
    }
  }
#undef STAGE_A
#undef STAGE_B
#undef BAR
#undef LDA_F
#undef LDB_F
#undef MFMA_PHASE
}

// ---------------------------------------------------------------------------
extern "C" void kernel_launch(void* const* d_in, const int* in_sizes, int n_in,
                              void* d_out, int out_size, void* d_ws, size_t ws_size,
                              hipStream_t stream) {
  const float* x     = (const float*)d_in[0];
  const float* theta = (const float*)d_in[1];
  const float* W1    = (const float*)d_in[2];
  const float* b1    = (const float*)d_in[3];
  const float* W2    = (const float*)d_in[4];
  const float* b2    = (const float*)d_in[5];
  float* out = (float*)d_out;

  const size_t W2SW_BYTES = (size_t)N_DIM * K_DIM * 2;   // 8 MiB
  uint16_t* W2sw = (uint16_t*)d_ws;
  uint16_t* Hsw  = (uint16_t*)((char*)d_ws + W2SW_BYTES);

  size_t avail = ws_size > W2SW_BYTES ? ws_size - W2SW_BYTES : 0;
  long CM = (long)(avail / ((size_t)K_DIM * 2));
  CM &= ~255L;                       // multiple of BM=256
  if (CM > M_TOT) CM = M_TOT;
  if (CM < 256) CM = 256;

  prep_w2<<<2048, 256, 0, stream>>>(W2, W2sw);

  for (long m0 = 0; m0 < M_TOT; m0 += CM) {
    long mc = M_TOT - m0;
    if (mc > CM) mc = CM;
    dim3 gA((unsigned)(mc / 64), K_DIM / 256);
    h_kernel<<<gA, 256, 0, stream>>>(x + m0 * N_DIM, theta, W1, b1, Hsw);
    unsigned ngb = (unsigned)((mc / BM) * (N_DIM / BN));
    gemm_kernel<<<ngb, 512, 0, stream>>>(Hsw, W2sw, b2, out + m0 * N_DIM);
  }
}